// Round 1
// baseline (282.282 us; speedup 1.0000x reference)
//
#include <hip/hip_runtime.h>
#include <stdint.h>

#define BATCH   262144
#define NROUTES 100000
#define NTIME   2016
#define DIM     256
#define KOUT    100
#define NTILES  7          // 112 padded output cols / 16
#define MT      128        // samples per workgroup

typedef __attribute__((ext_vector_type(8))) short bf16x8;   // 8 bf16 in 4 VGPRs
typedef __attribute__((ext_vector_type(4))) float f32x4;

// workspace layout
#define WS_W_BYTES  (NTILES * 8 * 64 * 16)                  // 57344 B, frag-ordered bf16 w
#define WS_RA_OFF   WS_W_BYTES                              // f32 [NROUTES][8]
#define WS_TB_OFF   (WS_RA_OFF + NROUTES * 8 * 4)           // f32 [NTIME][8]

static __device__ __forceinline__ uint32_t pk_bf16(float a, float b) {
  uint32_t ua = __builtin_bit_cast(uint32_t, a);
  uint32_t ub = __builtin_bit_cast(uint32_t, b);
  return (ua >> 16) | (ub & 0xFFFF0000u);   // truncate-to-bf16, pack low|high
}

// ---------------------------------------------------------------------------
// Prep: (1) w -> bf16 B-fragment order (zero-padded cols 100..111)
//       (2) RA[route] = route_table[route] @ mode_a   (f32, exact)
//       (3) TB[time]  = time_table[time]  @ mode_b
// ---------------------------------------------------------------------------
__global__ __launch_bounds__(256) void prep_kernel(
    const float* __restrict__ route_table,
    const float* __restrict__ time_table,
    const float* __restrict__ w,
    const float* __restrict__ mode_a,
    const float* __restrict__ mode_b,
    uint8_t* __restrict__ ws)
{
  const int b   = blockIdx.x;
  const int tid = threadIdx.x;

  if (b < 14) {                                   // ---- w fragments ----
    const int u = b * 256 + tid;                  // [0, 3584)
    const int lane = u & 63;
    const int frag = u >> 6;                      // ks*7 + nt
    const int ks = frag / NTILES;
    const int nt = frag % NTILES;
    const int n  = nt * 16 + (lane & 15);         // output col
    const int k0 = ks * 32 + (lane >> 4) * 8;     // k of element j=0
    uint32_t pk[4];
    #pragma unroll
    for (int p = 0; p < 4; ++p) {
      uint32_t lohi[2];
      #pragma unroll
      for (int q = 0; q < 2; ++q) {
        const int j = p * 2 + q;
        float v = (n < KOUT) ? w[(size_t)(k0 + j) * KOUT + n] : 0.0f;
        uint32_t uu = __builtin_bit_cast(uint32_t, v);
        uu += 0x7FFFu + ((uu >> 16) & 1u);        // RNE to bf16
        lohi[q] = uu >> 16;
      }
      pk[p] = lohi[0] | (lohi[1] << 16);
    }
    ((uint4*)ws)[u] = make_uint4(pk[0], pk[1], pk[2], pk[3]);
    return;
  }

  // ---- projection tables, wave-per-row, 16 rows per wave ----
  const float* tab; const float* proj; float* out8; int nrows; int wg;
  if (b < 14 + 32) { tab = time_table;  proj = mode_b; out8 = (float*)(ws + WS_TB_OFF); nrows = NTIME;   wg = b - 14; }
  else             { tab = route_table; proj = mode_a; out8 = (float*)(ws + WS_RA_OFF); nrows = NROUTES; wg = b - 46; }

  const int wave = tid >> 6, lane = tid & 63;
  float A[4][5];                                  // proj rows 4*lane..4*lane+3
  #pragma unroll
  for (int j = 0; j < 4; ++j)
    #pragma unroll
    for (int i = 0; i < 5; ++i)
      A[j][i] = proj[(4 * lane + j) * 5 + i];

  const int row0 = (wg * 4 + wave) * 16;
  for (int rr = 0; rr < 16; ++rr) {
    const int row = row0 + rr;
    if (row >= nrows) return;
    const float4 r4 = *(const float4*)(tab + (size_t)row * DIM + 4 * lane);
    float p[5];
    #pragma unroll
    for (int i = 0; i < 5; ++i)
      p[i] = r4.x * A[0][i] + r4.y * A[1][i] + r4.z * A[2][i] + r4.w * A[3][i];
    #pragma unroll
    for (int off = 32; off >= 1; off >>= 1)
      #pragma unroll
      for (int i = 0; i < 5; ++i)
        p[i] += __shfl_xor(p[i], off, 64);
    if (lane == 0) {
      float* o = out8 + (size_t)row * 8;
      o[0] = p[0]; o[1] = p[1]; o[2] = p[2]; o[3] = p[3]; o[4] = p[4];
    }
  }
}

// ---------------------------------------------------------------------------
// Main: gather r,t -> x=bf16(r*t) in A-frag order in LDS -> MFMA y = x @ w
//       -> epilogue relu-dot(fc_w) + sigmoid part from RA/TB gathers
// ---------------------------------------------------------------------------
__global__ __launch_bounds__(256, 2) void main_kernel(
    const int*   __restrict__ route_idx,
    const int*   __restrict__ time_idx,
    const float* __restrict__ route_table,
    const float* __restrict__ time_table,
    const float* __restrict__ mode_bias,
    const float* __restrict__ fc_w,
    const float* __restrict__ fc_b,
    const uint8_t* __restrict__ ws,
    float* __restrict__ out)
{
  __shared__ uint4 xf[(MT / 16) * 8 * 64];        // 4096 * 16B = 64 KiB, frag-linear
  const int tid = threadIdx.x;
  const int m0  = blockIdx.x * MT;

  // ---- stage x = bf16(r*t), directly in MFMA A-fragment order ----
  {
    const int row  = tid >> 1;                    // 2 threads per sample row
    const int half = tid & 1;                     // each does 128 of 256 k's
    const int n = m0 + row;
    const size_t ri = (size_t)route_idx[n];
    const size_t ti = (size_t)time_idx[n];
    const float4* rp = (const float4*)(route_table + ri * DIM + half * 128);
    const float4* tp = (const float4*)(time_table  + ti * DIM + half * 128);
    const int mtile = row >> 4;
    const int rlow  = row & 15;
    #pragma unroll
    for (int i = 0; i < 16; ++i) {                // 8 k's per iter
      float4 r0 = rp[2 * i],     t0 = tp[2 * i];
      float4 r1 = rp[2 * i + 1], t1 = tp[2 * i + 1];
      uint4 v;
      v.x = pk_bf16(r0.x * t0.x, r0.y * t0.y);
      v.y = pk_bf16(r0.z * t0.z, r0.w * t0.w);
      v.z = pk_bf16(r1.x * t1.x, r1.y * t1.y);
      v.w = pk_bf16(r1.z * t1.z, r1.w * t1.w);
      const int ks   = half * 4 + (i >> 2);       // k_base = half*128 + i*8
      const int quad = i & 3;
      xf[(mtile * 8 + ks) * 64 + quad * 16 + rlow] = v;
    }
  }
  __syncthreads();

  // ---- MFMA: y[128][112] = x @ w ----
  const int wave = tid >> 6;
  const int lane = tid & 63;
  const int col  = lane & 15;
  const int quad = lane >> 4;
  const bf16x8* wfr = (const bf16x8*)ws;          // frag-ordered w
  const int mt0 = wave * 2, mt1 = wave * 2 + 1;   // rows [wave*32, wave*32+32)

  f32x4 acc[2][NTILES];
  #pragma unroll
  for (int mt = 0; mt < 2; ++mt)
    #pragma unroll
    for (int nt = 0; nt < NTILES; ++nt)
      acc[mt][nt] = (f32x4){0.f, 0.f, 0.f, 0.f};

  #pragma unroll
  for (int ks = 0; ks < 8; ++ks) {
    bf16x8 a0 = ((const bf16x8*)xf)[(mt0 * 8 + ks) * 64 + lane];
    bf16x8 a1 = ((const bf16x8*)xf)[(mt1 * 8 + ks) * 64 + lane];
    bf16x8 wf[NTILES];
    #pragma unroll
    for (int nt = 0; nt < NTILES; ++nt)
      wf[nt] = wfr[(ks * NTILES + nt) * 64 + lane];
    #pragma unroll
    for (int nt = 0; nt < NTILES; ++nt) {
      acc[0][nt] = __builtin_amdgcn_mfma_f32_16x16x32_bf16(a0, wf[nt], acc[0][nt], 0, 0, 0);
      acc[1][nt] = __builtin_amdgcn_mfma_f32_16x16x32_bf16(a1, wf[nt], acc[1][nt], 0, 0, 0);
    }
  }

  // ---- epilogue 1: g[row] = sum_k relu(y)·fc_w[k]  (16-lane butterfly) ----
  float fcw_l[NTILES];
  #pragma unroll
  for (int nt = 0; nt < NTILES; ++nt) {
    const int n = nt * 16 + col;
    fcw_l[nt] = (n < KOUT) ? fc_w[n] : 0.0f;
  }
  float sred[2][4];
  #pragma unroll
  for (int mt = 0; mt < 2; ++mt)
    #pragma unroll
    for (int reg = 0; reg < 4; ++reg) {
      float s = 0.f;
      #pragma unroll
      for (int nt = 0; nt < NTILES; ++nt)
        s += fmaxf(acc[mt][nt][reg], 0.f) * fcw_l[nt];
      #pragma unroll
      for (int off = 1; off < 16; off <<= 1)
        s += __shfl_xor(s, off, 64);              // stays within 16-lane group
      sred[mt][reg] = s;
    }

  __syncthreads();                                // everyone done reading xf
  float* yg = (float*)xf;                         // reuse LDS for 128 row sums
  if (col == 0) {
    #pragma unroll
    for (int mt = 0; mt < 2; ++mt)
      #pragma unroll
      for (int reg = 0; reg < 4; ++reg)
        yg[wave * 32 + mt * 16 + quad * 4 + reg] = sred[mt][reg];
  }
  __syncthreads();

  // ---- epilogue 2: + sigmoid part from precomputed RA/TB, write out ----
  if (tid < MT) {
    const int n = m0 + tid;
    const size_t ri = (size_t)route_idx[n];
    const size_t ti = (size_t)time_idx[n];
    const float* ra = (const float*)(ws + WS_RA_OFF) + ri * 8;
    const float* tb = (const float*)(ws + WS_TB_OFF) + ti * 8;
    float rav[5], tbv[5];
    #pragma unroll
    for (int i = 0; i < 5; ++i) { rav[i] = ra[i]; tbv[i] = tb[i]; }
    float o = fc_b[0] + yg[tid];
    #pragma unroll
    for (int i = 0; i < 5; ++i)
      #pragma unroll
      for (int j = 0; j < 5; ++j) {
        const float z  = rav[i] * tbv[j] + mode_bias[i * 5 + j];
        const float sg = 1.0f / (1.0f + __expf(-z));
        o += sg * fc_w[KOUT + i * 5 + j];
      }
    out[n] = o;
  }
}

// ---------------------------------------------------------------------------
extern "C" void kernel_launch(void* const* d_in, const int* in_sizes, int n_in,
                              void* d_out, int out_size, void* d_ws, size_t ws_size,
                              hipStream_t stream)
{
  const int*   route_idx   = (const int*)d_in[0];
  const int*   time_idx    = (const int*)d_in[1];
  const float* route_table = (const float*)d_in[2];
  const float* time_table  = (const float*)d_in[3];
  const float* w           = (const float*)d_in[4];
  const float* mode_a      = (const float*)d_in[5];
  const float* mode_b      = (const float*)d_in[6];
  const float* mode_bias   = (const float*)d_in[7];
  const float* fc_w        = (const float*)d_in[8];
  const float* fc_b        = (const float*)d_in[9];
  uint8_t* ws  = (uint8_t*)d_ws;
  float*   out = (float*)d_out;

  // prep grid: 14 blocks (w frags) + 32 (TB) + ceil(100000/64)=1563 (RA)
  prep_kernel<<<14 + 32 + 1563, 256, 0, stream>>>(route_table, time_table, w,
                                                  mode_a, mode_b, ws);
  main_kernel<<<BATCH / MT, 256, 0, stream>>>(route_idx, time_idx,
                                              route_table, time_table,
                                              mode_bias, fc_w, fc_b, ws, out);
}

// Round 2
// 245.378 us; speedup vs baseline: 1.1504x; 1.1504x over previous
//
#include <hip/hip_runtime.h>
#include <stdint.h>

#define BATCH   262144
#define NROUTES 100000
#define NTIME   2016
#define DIM     256
#define KOUT    100
#define NTILES  7          // 112 padded output cols / 16

typedef __attribute__((ext_vector_type(8))) short bf16x8;   // 8 bf16 (4 VGPRs)
typedef __attribute__((ext_vector_type(4))) float f32x4;

// ---- workspace layout ----
#define WS_W_BYTES  (NTILES * 8 * 64 * 16)                  // 57344 B frag-ordered bf16 w
#define WS_RA_OFF   ((size_t)WS_W_BYTES)                    // f32 [NROUTES][8]
#define WS_TB_OFF   (WS_RA_OFF + (size_t)NROUTES * 32)      // f32 [NTIME][8]
#define WS_RT16_OFF (WS_TB_OFF + (size_t)NTIME * 32)        // bf16 [NROUTES][256]
#define WS_TT16_OFF (WS_RT16_OFF + (size_t)NROUTES * 512)   // bf16 [NTIME][256]
#define WS_NEED     (WS_TT16_OFF + (size_t)NTIME * 512)     // ~55.6 MB

static __device__ __forceinline__ uint32_t rne_bf16(float f) {
  uint32_t u = __builtin_bit_cast(uint32_t, f);
  u += 0x7FFFu + ((u >> 16) & 1u);
  return u >> 16;
}
static __device__ __forceinline__ uint32_t pk_rne(float a, float b) {
  return rne_bf16(a) | (rne_bf16(b) << 16);
}
// pack truncate-to-bf16: low16 = a, high16 = b (1 v_perm)
static __device__ __forceinline__ uint32_t pk_trunc(float a, float b) {
  return __builtin_amdgcn_perm(__builtin_bit_cast(uint32_t, b),
                               __builtin_bit_cast(uint32_t, a), 0x07060302u);
}
// product of two bf16 pairs -> bf16 pair (truncated)
static __device__ __forceinline__ uint32_t mulpk(uint32_t a, uint32_t b) {
  float alo = __builtin_bit_cast(float, a << 16);
  float blo = __builtin_bit_cast(float, b << 16);
  float ahi = __builtin_bit_cast(float, a & 0xFFFF0000u);
  float bhi = __builtin_bit_cast(float, b & 0xFFFF0000u);
  return __builtin_amdgcn_perm(__builtin_bit_cast(uint32_t, ahi * bhi),
                               __builtin_bit_cast(uint32_t, alo * blo), 0x07060302u);
}

// ---------------------------------------------------------------------------
// Prep: (1) w -> bf16 B-frag order (b<14)
//       (2) TB + bf16 time table   (126 blocks, 16 rows each)
//       (3) RA + bf16 route table  (6250 blocks, 16 rows each)
// ---------------------------------------------------------------------------
__global__ __launch_bounds__(256) void prep_kernel(
    const float* __restrict__ route_table,
    const float* __restrict__ time_table,
    const float* __restrict__ w,
    const float* __restrict__ mode_a,
    const float* __restrict__ mode_b,
    uint8_t* __restrict__ ws, int do16)
{
  const int b   = blockIdx.x;
  const int tid = threadIdx.x;

  if (b < 14) {                                   // ---- w fragments ----
    const int u = b * 256 + tid;                  // [0, 3584)
    const int lane = u & 63;
    const int frag = u >> 6;                      // ks*7 + nt
    const int ks = frag / NTILES;
    const int nt = frag % NTILES;
    const int n  = nt * 16 + (lane & 15);
    const int k0 = ks * 32 + (lane >> 4) * 8;
    uint32_t pk[4];
    #pragma unroll
    for (int p = 0; p < 4; ++p) {
      float v0 = (n < KOUT) ? w[(size_t)(k0 + 2 * p) * KOUT + n] : 0.0f;
      float v1 = (n < KOUT) ? w[(size_t)(k0 + 2 * p + 1) * KOUT + n] : 0.0f;
      pk[p] = pk_rne(v0, v1);
    }
    ((uint4*)ws)[u] = make_uint4(pk[0], pk[1], pk[2], pk[3]);
    return;
  }

  const float* tab; const float* proj; float* outp; uint8_t* out16; int base;
  if (b < 14 + 126) {
    tab = time_table;  proj = mode_b; outp = (float*)(ws + WS_TB_OFF);
    out16 = ws + WS_TT16_OFF; base = (b - 14) * 16;
  } else {
    tab = route_table; proj = mode_a; outp = (float*)(ws + WS_RA_OFF);
    out16 = ws + WS_RT16_OFF; base = (b - 140) * 16;
  }

  const int wave = tid >> 6, lane = tid & 63;
  float A[4][5];                                  // proj rows 4*lane..4*lane+3
  #pragma unroll
  for (int j = 0; j < 4; ++j)
    #pragma unroll
    for (int i = 0; i < 5; ++i)
      A[j][i] = proj[(4 * lane + j) * 5 + i];

  const int row0 = base + wave * 4;               // 4 rows per wave
  float4 v[4];
  #pragma unroll
  for (int rr = 0; rr < 4; ++rr)
    v[rr] = *(const float4*)(tab + (size_t)(row0 + rr) * DIM + 4 * lane);

  #pragma unroll
  for (int rr = 0; rr < 4; ++rr) {
    const int row = row0 + rr;
    if (do16) {
      uint2 o;
      o.x = pk_rne(v[rr].x, v[rr].y);
      o.y = pk_rne(v[rr].z, v[rr].w);
      *(uint2*)(out16 + (size_t)row * 512 + lane * 8) = o;
    }
    float p[5];
    #pragma unroll
    for (int i = 0; i < 5; ++i)
      p[i] = v[rr].x * A[0][i] + v[rr].y * A[1][i] + v[rr].z * A[2][i] + v[rr].w * A[3][i];
    #pragma unroll
    for (int off = 32; off >= 1; off >>= 1)
      #pragma unroll
      for (int i = 0; i < 5; ++i)
        p[i] += __shfl_xor(p[i], off, 64);
    if (lane == 0) {
      float* o = outp + (size_t)row * 8;
      o[0] = p[0]; o[1] = p[1]; o[2] = p[2]; o[3] = p[3]; o[4] = p[4];
    }
  }
}

// ---------------------------------------------------------------------------
// Main: wave = one 16-sample mtile. Gather r,t chunks per-lane directly in
// A-frag order (row=lane&15, k=quad*8+j), products in registers, no x-LDS,
// no barrier in hot loop. TAB16: gather bf16 tables from ws; else f32 tables.
// ---------------------------------------------------------------------------
template<int TAB16>
__global__ __launch_bounds__(256, 3) void main_kernel(
    const int*   __restrict__ route_idx,
    const int*   __restrict__ time_idx,
    const float* __restrict__ route_table,
    const float* __restrict__ time_table,
    const float* __restrict__ mode_bias,
    const float* __restrict__ fc_w,
    const float* __restrict__ fc_b,
    const uint8_t* __restrict__ ws,
    float* __restrict__ out)
{
  __shared__ float yg[64];
  const int tid  = threadIdx.x;
  const int wave = tid >> 6, lane = tid & 63;
  const int col  = lane & 15, quad = lane >> 4;
  const int m0   = blockIdx.x * 64 + wave * 16;   // this wave's 16 samples
  const size_t ri = (size_t)route_idx[m0 + col];  // this lane's sample row
  const size_t ti = (size_t)time_idx[m0 + col];

  uint4 rw[8], tw[8];                             // lane's 64 r,t elems (bf16)
  if (TAB16) {
    const uint8_t* rb = ws + WS_RT16_OFF + ri * 512 + quad * 16;
    const uint8_t* tb = ws + WS_TT16_OFF + ti * 512 + quad * 16;
    #pragma unroll
    for (int ks = 0; ks < 8; ++ks) {              // byte off = ks*64 (k=ks*32)
      rw[ks] = *(const uint4*)(rb + ks * 64);
      tw[ks] = *(const uint4*)(tb + ks * 64);
    }
  }

  f32x4 acc[NTILES];
  #pragma unroll
  for (int nt = 0; nt < NTILES; ++nt) acc[nt] = (f32x4){0.f, 0.f, 0.f, 0.f};
  const bf16x8* wfr = (const bf16x8*)ws;

  #pragma unroll
  for (int ks = 0; ks < 8; ++ks) {
    uint4 p;
    if (TAB16) {
      p.x = mulpk(rw[ks].x, tw[ks].x);
      p.y = mulpk(rw[ks].y, tw[ks].y);
      p.z = mulpk(rw[ks].z, tw[ks].z);
      p.w = mulpk(rw[ks].w, tw[ks].w);
    } else {
      const float4* rp = (const float4*)(route_table + ri * DIM + ks * 32 + quad * 8);
      const float4* tp = (const float4*)(time_table  + ti * DIM + ks * 32 + quad * 8);
      float4 r0 = rp[0], r1 = rp[1], t0 = tp[0], t1 = tp[1];
      p.x = pk_trunc(r0.x * t0.x, r0.y * t0.y);
      p.y = pk_trunc(r0.z * t0.z, r0.w * t0.w);
      p.z = pk_trunc(r1.x * t1.x, r1.y * t1.y);
      p.w = pk_trunc(r1.z * t1.z, r1.w * t1.w);
    }
    const bf16x8 a = __builtin_bit_cast(bf16x8, p);
    #pragma unroll
    for (int nt = 0; nt < NTILES; ++nt)
      acc[nt] = __builtin_amdgcn_mfma_f32_16x16x32_bf16(a, wfr[(ks * NTILES + nt) * 64 + lane],
                                                        acc[nt], 0, 0, 0);
  }

  // ---- epilogue 1: per-sample relu-dot with fc_w (16-lane butterfly) ----
  float fcw_l[NTILES];
  #pragma unroll
  for (int nt = 0; nt < NTILES; ++nt) {
    const int n = nt * 16 + col;
    fcw_l[nt] = (n < KOUT) ? fc_w[n] : 0.0f;
  }
  #pragma unroll
  for (int reg = 0; reg < 4; ++reg) {
    float s = 0.f;
    #pragma unroll
    for (int nt = 0; nt < NTILES; ++nt)
      s += fmaxf(acc[nt][reg], 0.f) * fcw_l[nt];
    #pragma unroll
    for (int off = 1; off < 16; off <<= 1)
      s += __shfl_xor(s, off, 64);                // stays within 16-lane group
    if (col == 0) yg[wave * 16 + quad * 4 + reg] = s;
  }
  __syncthreads();

  // ---- epilogue 2: + sigmoid part from precomputed RA/TB ----
  if (tid < 64) {
    const int n = blockIdx.x * 64 + tid;
    const size_t ri2 = (size_t)route_idx[n];
    const size_t ti2 = (size_t)time_idx[n];
    const float* ra = (const float*)(ws + WS_RA_OFF) + ri2 * 8;
    const float* tb = (const float*)(ws + WS_TB_OFF) + ti2 * 8;
    float rav[5], tbv[5];
    #pragma unroll
    for (int i = 0; i < 5; ++i) { rav[i] = ra[i]; tbv[i] = tb[i]; }
    float o = fc_b[0] + yg[tid];
    #pragma unroll
    for (int i = 0; i < 5; ++i)
      #pragma unroll
      for (int j = 0; j < 5; ++j) {
        const float z  = rav[i] * tbv[j] + mode_bias[i * 5 + j];
        const float sg = 1.0f / (1.0f + __expf(-z));
        o += sg * fc_w[KOUT + i * 5 + j];
      }
    out[n] = o;
  }
}

// ---------------------------------------------------------------------------
extern "C" void kernel_launch(void* const* d_in, const int* in_sizes, int n_in,
                              void* d_out, int out_size, void* d_ws, size_t ws_size,
                              hipStream_t stream)
{
  const int*   route_idx   = (const int*)d_in[0];
  const int*   time_idx    = (const int*)d_in[1];
  const float* route_table = (const float*)d_in[2];
  const float* time_table  = (const float*)d_in[3];
  const float* w           = (const float*)d_in[4];
  const float* mode_a      = (const float*)d_in[5];
  const float* mode_b      = (const float*)d_in[6];
  const float* mode_bias   = (const float*)d_in[7];
  const float* fc_w        = (const float*)d_in[8];
  const float* fc_b        = (const float*)d_in[9];
  uint8_t* ws  = (uint8_t*)d_ws;
  float*   out = (float*)d_out;

  const int big = (ws_size >= WS_NEED) ? 1 : 0;   // constant across calls

  // 14 (w frags) + 126 (TB, 2016 rows) + 6250 (RA, 100000 rows)
  prep_kernel<<<6390, 256, 0, stream>>>(route_table, time_table, w,
                                        mode_a, mode_b, ws, big);
  if (big)
    main_kernel<1><<<BATCH / 64, 256, 0, stream>>>(route_idx, time_idx,
                                                   route_table, time_table,
                                                   mode_bias, fc_w, fc_b, ws, out);
  else
    main_kernel<0><<<BATCH / 64, 256, 0, stream>>>(route_idx, time_idx,
                                                   route_table, time_table,
                                                   mode_bias, fc_w, fc_b, ws, out);
}

// Round 3
// 225.497 us; speedup vs baseline: 1.2518x; 1.0882x over previous
//
#include <hip/hip_runtime.h>
#include <stdint.h>

#define BATCH   262144
#define NROUTES 100000
#define NTIME   2016
#define DIM     256
#define KOUT    100
#define NTILES  7          // 112 padded output cols / 16

typedef __attribute__((ext_vector_type(2))) float f32x2;
typedef __attribute__((ext_vector_type(4))) float f32x4;

// ---- workspace layout ----
#define WS_WFRAG_BYTES ((size_t)(NTILES * 8 * 64 * 8))      // 28672 B fp8 w frags
#define WS_RA_OFF   (WS_WFRAG_BYTES)                        // f32 [NROUTES][8]
#define WS_TB_OFF   (WS_RA_OFF + (size_t)NROUTES * 32)      // f32 [NTIME][8]
#define WS_RT8_OFF  (WS_TB_OFF + (size_t)NTIME * 32)        // fp8 [NROUTES][256] permuted
#define WS_TT8_OFF  (WS_RT8_OFF + (size_t)NROUTES * 256)    // fp8 [NTIME][256] permuted
#define WS_NEED     (WS_TT8_OFF + (size_t)NTIME * 256)      // ~29.4 MB

// fused DPP lane-shift + add (pure VALU, no LDS)
template<int CTRL>
static __device__ __forceinline__ float dpp_add(float x) {
  int s = __builtin_amdgcn_update_dpp(0, __builtin_bit_cast(int, x), CTRL, 0xF, 0xF, true);
  return x + __builtin_bit_cast(float, s);
}
// full 64-lane sum -> lane 63 (canonical GCN sequence)
static __device__ __forceinline__ float wave_sum63(float x) {
  x = dpp_add<0x111>(x);  // row_shr:1
  x = dpp_add<0x112>(x);  // row_shr:2
  x = dpp_add<0x114>(x);  // row_shr:4
  x = dpp_add<0x118>(x);  // row_shr:8
  x = dpp_add<0x142>(x);  // row_bcast:15
  x = dpp_add<0x143>(x);  // row_bcast:31
  return x;
}
// 16-lane-group sum, broadcast to all 16 lanes (xor1, xor2, ror4, ror8)
static __device__ __forceinline__ float sum16_all(float x) {
  x = dpp_add<0x0B1>(x);  // quad_perm [1,0,3,2]
  x = dpp_add<0x04E>(x);  // quad_perm [2,3,0,1]
  x = dpp_add<0x124>(x);  // row_ror:4
  x = dpp_add<0x128>(x);  // row_ror:8
  return x;
}

// ---------------------------------------------------------------------------
// Prep: (1) w -> fp8 B-frag order (b<14), zero-padded cols 100..111
//       (2) TB + fp8 time table   (126 blocks, 16 rows)
//       (3) RA + fp8 route table  (6250 blocks, 16 rows)
// fp8 rows stored PERMUTED: logical k -> phys (ks>>1)*64 + quad*16 + (ks&1)*8 + j
// with ks=k>>5, quad=(k>>3)&3, j=k&7.  Values scaled x8.
// ---------------------------------------------------------------------------
__global__ __launch_bounds__(256) void prep_kernel(
    const float* __restrict__ route_table,
    const float* __restrict__ time_table,
    const float* __restrict__ w,
    const float* __restrict__ mode_a,
    const float* __restrict__ mode_b,
    uint8_t* __restrict__ ws, int do8)
{
  const int b   = blockIdx.x;
  const int tid = threadIdx.x;

  if (b < 14) {                                   // ---- w fragments (fp8) ----
    const int u = b * 256 + tid;                  // [0, 3584)
    const int lane = u & 63;
    const int frag = u >> 6;                      // ks*7 + nt
    const int ks = frag / NTILES;
    const int nt = frag % NTILES;
    const int n  = nt * 16 + (lane & 15);
    const int k0 = ks * 32 + (lane >> 4) * 8;
    float v[8];
    #pragma unroll
    for (int j = 0; j < 8; ++j)
      v[j] = (n < KOUT) ? w[(size_t)(k0 + j) * KOUT + n] : 0.0f;
    uint32_t d0 = 0, d1 = 0;
    d0 = __builtin_amdgcn_cvt_pk_fp8_f32(v[0], v[1], d0, false);
    d0 = __builtin_amdgcn_cvt_pk_fp8_f32(v[2], v[3], d0, true);
    d1 = __builtin_amdgcn_cvt_pk_fp8_f32(v[4], v[5], d1, false);
    d1 = __builtin_amdgcn_cvt_pk_fp8_f32(v[6], v[7], d1, true);
    ((uint2*)ws)[u] = make_uint2(d0, d1);
    return;
  }

  const float* tab; const float* proj; float* outp; uint8_t* out8; int base;
  if (b < 14 + 126) {
    tab = time_table;  proj = mode_b; outp = (float*)(ws + WS_TB_OFF);
    out8 = ws + WS_TT8_OFF; base = (b - 14) * 16;
  } else {
    tab = route_table; proj = mode_a; outp = (float*)(ws + WS_RA_OFF);
    out8 = ws + WS_RT8_OFF; base = (b - 140) * 16;
  }

  const int wave = tid >> 6, lane = tid & 63;
  float A[4][5];                                  // proj rows 4*lane..4*lane+3
  #pragma unroll
  for (int j = 0; j < 4; ++j)
    #pragma unroll
    for (int i = 0; i < 5; ++i)
      A[j][i] = proj[(4 * lane + j) * 5 + i];

  // phys offset of this lane's 4 fp8 bytes (logical k = 4*lane..4*lane+3)
  const int p0 = (lane >> 4) * 64 + ((lane >> 1) & 3) * 16 +
                 ((lane >> 3) & 1) * 8 + (lane & 1) * 4;

  const int row0 = base + wave * 4;               // 4 rows per wave
  float4 v[4];
  #pragma unroll
  for (int rr = 0; rr < 4; ++rr)
    v[rr] = *(const float4*)(tab + (size_t)(row0 + rr) * DIM + 4 * lane);

  #pragma unroll
  for (int rr = 0; rr < 4; ++rr) {
    const int row = row0 + rr;
    if (do8) {                                    // fp8 emission, scaled x8
      uint32_t u = 0;
      u = __builtin_amdgcn_cvt_pk_fp8_f32(8.f * v[rr].x, 8.f * v[rr].y, u, false);
      u = __builtin_amdgcn_cvt_pk_fp8_f32(8.f * v[rr].z, 8.f * v[rr].w, u, true);
      *(uint32_t*)(out8 + (size_t)row * 256 + p0) = u;
    }
    float p[5];
    #pragma unroll
    for (int i = 0; i < 5; ++i) {
      float s = v[rr].x * A[0][i] + v[rr].y * A[1][i] + v[rr].z * A[2][i] + v[rr].w * A[3][i];
      p[i] = wave_sum63(s);
    }
    if (lane == 63) {
      float* o = outp + (size_t)row * 8;
      *(f32x4*)o = (f32x4){p[0], p[1], p[2], p[3]};
      o[4] = p[4];
    }
  }
}

// ---------------------------------------------------------------------------
// Main: wave = one 16-sample mtile, no LDS, no barriers.
// TAB8: gather permuted fp8 rows (64B/lane, line-shared); else f32 fallback.
// ---------------------------------------------------------------------------
template<int TAB8>
__global__ __launch_bounds__(256, 4) void main_kernel(
    const int*   __restrict__ route_idx,
    const int*   __restrict__ time_idx,
    const float* __restrict__ route_table,
    const float* __restrict__ time_table,
    const float* __restrict__ mode_bias,
    const float* __restrict__ fc_w,
    const float* __restrict__ fc_b,
    const uint8_t* __restrict__ ws,
    float* __restrict__ out)
{
  const int tid  = threadIdx.x;
  const int wave = tid >> 6, lane = tid & 63;
  const int col  = lane & 15, quad = lane >> 4;
  const int m0   = blockIdx.x * 64 + wave * 16;
  const size_t ri = (size_t)route_idx[m0 + col];
  const size_t ti = (size_t)time_idx[m0 + col];
  const bool desig = (quad == (col >> 2));        // one lane per sample

  // early independent loads: sigmoid-part inputs for designated lanes
  f32x4 ra0; float ra4; f32x4 tb0; float tb4;
  if (desig) {
    const float* ra = (const float*)(ws + WS_RA_OFF) + ri * 8;
    const float* tb = (const float*)(ws + WS_TB_OFF) + ti * 8;
    ra0 = *(const f32x4*)ra; ra4 = ra[4];
    tb0 = *(const f32x4*)tb; tb4 = tb[4];
  }

  uint4 rw[4], tw[4];                             // this lane's 64B of r and t
  if (TAB8) {
    const uint8_t* rb = ws + WS_RT8_OFF + ri * 256 + quad * 16;
    const uint8_t* tb = ws + WS_TT8_OFF + ti * 256 + quad * 16;
    #pragma unroll
    for (int i = 0; i < 4; ++i) {
      rw[i] = *(const uint4*)(rb + i * 64);
      tw[i] = *(const uint4*)(tb + i * 64);
    }
  }

  float fcw_l[NTILES];                            // fc_w with the 1/64 x-scale
  #pragma unroll
  for (int nt = 0; nt < NTILES; ++nt) {
    const int n = nt * 16 + col;
    fcw_l[nt] = (n < KOUT) ? fc_w[n] * 0.015625f : 0.0f;
  }

  f32x4 acc[NTILES];
  #pragma unroll
  for (int nt = 0; nt < NTILES; ++nt) acc[nt] = (f32x4){0.f, 0.f, 0.f, 0.f};
  const uint2* wfr = (const uint2*)ws;

  #pragma unroll
  for (int ks = 0; ks < 8; ++ks) {
    uint32_t p0, p1;
    if (TAB8) {
      const int i = ks >> 1;
      const uint32_t ra = (ks & 1) ? rw[i].z : rw[i].x;
      const uint32_t rb = (ks & 1) ? rw[i].w : rw[i].y;
      const uint32_t ta = (ks & 1) ? tw[i].z : tw[i].x;
      const uint32_t tb = (ks & 1) ? tw[i].w : tw[i].y;
      f32x2 r01 = __builtin_amdgcn_cvt_pk_f32_fp8(ra, false);
      f32x2 r23 = __builtin_amdgcn_cvt_pk_f32_fp8(ra, true);
      f32x2 r45 = __builtin_amdgcn_cvt_pk_f32_fp8(rb, false);
      f32x2 r67 = __builtin_amdgcn_cvt_pk_f32_fp8(rb, true);
      f32x2 t01 = __builtin_amdgcn_cvt_pk_f32_fp8(ta, false);
      f32x2 t23 = __builtin_amdgcn_cvt_pk_f32_fp8(ta, true);
      f32x2 t45 = __builtin_amdgcn_cvt_pk_f32_fp8(tb, false);
      f32x2 t67 = __builtin_amdgcn_cvt_pk_f32_fp8(tb, true);
      f32x2 x01 = r01 * t01, x23 = r23 * t23, x45 = r45 * t45, x67 = r67 * t67;
      p0 = 0; p1 = 0;
      p0 = __builtin_amdgcn_cvt_pk_fp8_f32(x01.x, x01.y, p0, false);
      p0 = __builtin_amdgcn_cvt_pk_fp8_f32(x23.x, x23.y, p0, true);
      p1 = __builtin_amdgcn_cvt_pk_fp8_f32(x45.x, x45.y, p1, false);
      p1 = __builtin_amdgcn_cvt_pk_fp8_f32(x67.x, x67.y, p1, true);
    } else {
      const float4* rp = (const float4*)(route_table + ri * DIM + ks * 32 + quad * 8);
      const float4* tp = (const float4*)(time_table  + ti * DIM + ks * 32 + quad * 8);
      float4 r0 = rp[0], r1 = rp[1], t0 = tp[0], t1 = tp[1];
      p0 = 0; p1 = 0;
      p0 = __builtin_amdgcn_cvt_pk_fp8_f32(64.f * r0.x * t0.x, 64.f * r0.y * t0.y, p0, false);
      p0 = __builtin_amdgcn_cvt_pk_fp8_f32(64.f * r0.z * t0.z, 64.f * r0.w * t0.w, p0, true);
      p1 = __builtin_amdgcn_cvt_pk_fp8_f32(64.f * r1.x * t1.x, 64.f * r1.y * t1.y, p1, false);
      p1 = __builtin_amdgcn_cvt_pk_fp8_f32(64.f * r1.z * t1.z, 64.f * r1.w * t1.w, p1, true);
    }
    const long a64 = __builtin_bit_cast(long, make_uint2(p0, p1));
    #pragma unroll
    for (int nt = 0; nt < NTILES; ++nt) {
      const long b64 = __builtin_bit_cast(long, wfr[(ks * NTILES + nt) * 64 + lane]);
      acc[nt] = __builtin_amdgcn_mfma_f32_16x16x32_fp8_fp8(a64, b64, acc[nt], 0, 0, 0);
    }
  }

  // ---- relu-dot with fc_w, reduced across the 16 col-lanes via DPP ----
  float s[4];
  #pragma unroll
  for (int reg = 0; reg < 4; ++reg) {
    float v = 0.f;
    #pragma unroll
    for (int nt = 0; nt < NTILES; ++nt)
      v += fmaxf(acc[nt][reg], 0.f) * fcw_l[nt];
    s[reg] = sum16_all(v);                        // all 16 lanes get the sum
  }

  // ---- designated lane finishes its sample: + sigmoid part, store ----
  if (desig) {
    const int m = col;                            // sample m, row = quad*4+(m&3)
    const float sa = (m & 1) ? s[1] : s[0];
    const float sb = (m & 1) ? s[3] : s[2];
    float o = fc_b[0] + ((m & 2) ? sb : sa);
    const float rav[5] = {ra0.x, ra0.y, ra0.z, ra0.w, ra4};
    const float tbv[5] = {tb0.x, tb0.y, tb0.z, tb0.w, tb4};
    #pragma unroll
    for (int i = 0; i < 5; ++i)
      #pragma unroll
      for (int j = 0; j < 5; ++j) {
        const float z  = rav[i] * tbv[j] + mode_bias[i * 5 + j];
        const float sg = 1.0f / (1.0f + __expf(-z));
        o += sg * fc_w[KOUT + i * 5 + j];
      }
    out[m0 + m] = o;
  }
}

// ---------------------------------------------------------------------------
extern "C" void kernel_launch(void* const* d_in, const int* in_sizes, int n_in,
                              void* d_out, int out_size, void* d_ws, size_t ws_size,
                              hipStream_t stream)
{
  const int*   route_idx   = (const int*)d_in[0];
  const int*   time_idx    = (const int*)d_in[1];
  const float* route_table = (const float*)d_in[2];
  const float* time_table  = (const float*)d_in[3];
  const float* w           = (const float*)d_in[4];
  const float* mode_a      = (const float*)d_in[5];
  const float* mode_b      = (const float*)d_in[6];
  const float* mode_bias   = (const float*)d_in[7];
  const float* fc_w        = (const float*)d_in[8];
  const float* fc_b        = (const float*)d_in[9];
  uint8_t* ws  = (uint8_t*)d_ws;
  float*   out = (float*)d_out;

  const int big = (ws_size >= WS_NEED) ? 1 : 0;   // constant across calls

  // 14 (w frags) + 126 (time rows) + 6250 (route rows)
  prep_kernel<<<6390, 256, 0, stream>>>(route_table, time_table, w,
                                        mode_a, mode_b, ws, big);
  if (big)
    main_kernel<1><<<BATCH / 64, 256, 0, stream>>>(route_idx, time_idx,
                                                   route_table, time_table,
                                                   mode_bias, fc_w, fc_b, ws, out);
  else
    main_kernel<0><<<BATCH / 64, 256, 0, stream>>>(route_idx, time_idx,
                                                   route_table, time_table,
                                                   mode_bias, fc_w, fc_b, ws, out);
}

// Round 4
// 203.318 us; speedup vs baseline: 1.3884x; 1.1091x over previous
//
#include <hip/hip_runtime.h>
#include <stdint.h>

#define BATCH   262144
#define NROUTES 100000
#define NTIME   2016
#define DIM     256
#define KOUT    100
#define NTILES  7          // 112 padded output cols / 16

typedef __attribute__((ext_vector_type(2))) float f32x2;
typedef __attribute__((ext_vector_type(4))) float f32x4;

// ---- workspace layout ----
#define WS_WFRAG_BYTES ((size_t)(NTILES * 8 * 64 * 8))      // 28672 B fp8 w frags
#define WS_RA_OFF   (WS_WFRAG_BYTES)                        // f32 [NROUTES][8]
#define WS_TB_OFF   (WS_RA_OFF + (size_t)NROUTES * 32)      // f32 [NTIME][8]
#define WS_RT8_OFF  (WS_TB_OFF + (size_t)NTIME * 32)        // fp8 [NROUTES][256] permuted
#define WS_TT8_OFF  (WS_RT8_OFF + (size_t)NROUTES * 256)    // fp8 [NTIME][256] permuted
#define WS_NEED     (WS_TT8_OFF + (size_t)NTIME * 256)      // ~29.4 MB

// fused DPP lane-shift + add (pure VALU, no LDS)
template<int CTRL>
static __device__ __forceinline__ float dpp_add(float x) {
  int s = __builtin_amdgcn_update_dpp(0, __builtin_bit_cast(int, x), CTRL, 0xF, 0xF, true);
  return x + __builtin_bit_cast(float, s);
}
// full 64-lane sum -> lane 63
static __device__ __forceinline__ float wave_sum63(float x) {
  x = dpp_add<0x111>(x);  // row_shr:1
  x = dpp_add<0x112>(x);  // row_shr:2
  x = dpp_add<0x114>(x);  // row_shr:4
  x = dpp_add<0x118>(x);  // row_shr:8
  x = dpp_add<0x142>(x);  // row_bcast:15
  x = dpp_add<0x143>(x);  // row_bcast:31
  return x;
}
// 16-lane-group sum, broadcast to all 16 lanes
static __device__ __forceinline__ float sum16_all(float x) {
  x = dpp_add<0x0B1>(x);  // quad_perm [1,0,3,2]
  x = dpp_add<0x04E>(x);  // quad_perm [2,3,0,1]
  x = dpp_add<0x124>(x);  // row_ror:4
  x = dpp_add<0x128>(x);  // row_ror:8
  return x;
}
static __device__ __forceinline__ float sigm(float z) {
  return __builtin_amdgcn_rcpf(1.0f + __expf(-z));
}

// ---------------------------------------------------------------------------
// Prep: (1) w -> fp8 B-frag order (b<14), zero-padded cols 100..111
//       (2) TB + fp8 time table   (126 blocks, 16 rows)
//       (3) RA + fp8 route table  (6250 blocks, 16 rows)
// fp8 rows PERMUTED: logical k -> phys (ks>>1)*64 + quad*16 + (ks&1)*8 + j
// with ks=k>>5, quad=(k>>3)&3, j=k&7.  Values scaled x8.
// ---------------------------------------------------------------------------
__global__ __launch_bounds__(256) void prep_kernel(
    const float* __restrict__ route_table,
    const float* __restrict__ time_table,
    const float* __restrict__ w,
    const float* __restrict__ mode_a,
    const float* __restrict__ mode_b,
    uint8_t* __restrict__ ws, int do8)
{
  const int b   = blockIdx.x;
  const int tid = threadIdx.x;

  if (b < 14) {                                   // ---- w fragments (fp8) ----
    const int u = b * 256 + tid;                  // [0, 3584)
    const int lane = u & 63;
    const int frag = u >> 6;                      // ks*7 + nt
    const int ks = frag / NTILES;
    const int nt = frag % NTILES;
    const int n  = nt * 16 + (lane & 15);
    const int k0 = ks * 32 + (lane >> 4) * 8;
    float v[8];
    #pragma unroll
    for (int j = 0; j < 8; ++j)
      v[j] = (n < KOUT) ? w[(size_t)(k0 + j) * KOUT + n] : 0.0f;
    uint32_t d0 = 0, d1 = 0;
    d0 = __builtin_amdgcn_cvt_pk_fp8_f32(v[0], v[1], d0, false);
    d0 = __builtin_amdgcn_cvt_pk_fp8_f32(v[2], v[3], d0, true);
    d1 = __builtin_amdgcn_cvt_pk_fp8_f32(v[4], v[5], d1, false);
    d1 = __builtin_amdgcn_cvt_pk_fp8_f32(v[6], v[7], d1, true);
    ((uint2*)ws)[u] = make_uint2(d0, d1);
    return;
  }

  const float* tab; const float* proj; float* outp; uint8_t* out8; int base;
  if (b < 14 + 126) {
    tab = time_table;  proj = mode_b; outp = (float*)(ws + WS_TB_OFF);
    out8 = ws + WS_TT8_OFF; base = (b - 14) * 16;
  } else {
    tab = route_table; proj = mode_a; outp = (float*)(ws + WS_RA_OFF);
    out8 = ws + WS_RT8_OFF; base = (b - 140) * 16;
  }

  const int wave = tid >> 6, lane = tid & 63;
  float A[4][5];                                  // proj rows 4*lane..4*lane+3
  #pragma unroll
  for (int j = 0; j < 4; ++j)
    #pragma unroll
    for (int i = 0; i < 5; ++i)
      A[j][i] = proj[(4 * lane + j) * 5 + i];

  // phys offset of this lane's 4 fp8 bytes (logical k = 4*lane..4*lane+3)
  const int p0 = (lane >> 4) * 64 + ((lane >> 1) & 3) * 16 +
                 ((lane >> 3) & 1) * 8 + (lane & 1) * 4;

  const int row0 = base + wave * 4;               // 4 rows per wave
  float4 v[4];
  #pragma unroll
  for (int rr = 0; rr < 4; ++rr)
    v[rr] = *(const float4*)(tab + (size_t)(row0 + rr) * DIM + 4 * lane);

  #pragma unroll
  for (int rr = 0; rr < 4; ++rr) {
    const int row = row0 + rr;
    if (do8) {                                    // fp8 emission, scaled x8
      uint32_t u = 0;
      u = __builtin_amdgcn_cvt_pk_fp8_f32(8.f * v[rr].x, 8.f * v[rr].y, u, false);
      u = __builtin_amdgcn_cvt_pk_fp8_f32(8.f * v[rr].z, 8.f * v[rr].w, u, true);
      *(uint32_t*)(out8 + (size_t)row * 256 + p0) = u;
    }
    float p[5];
    #pragma unroll
    for (int i = 0; i < 5; ++i) {
      float s = v[rr].x * A[0][i] + v[rr].y * A[1][i] + v[rr].z * A[2][i] + v[rr].w * A[3][i];
      p[i] = wave_sum63(s);
    }
    if (lane == 63) {
      float* o = outp + (size_t)row * 8;
      *(f32x4*)o = (f32x4){p[0], p[1], p[2], p[3]};
      o[4] = p[4];
    }
  }
}

// ---------------------------------------------------------------------------
// Main: wave = one 16-sample mtile. w-frags staged in LDS once per block;
// gathers issued early to overlap the fill. Sigmoid tail distributed over
// the 4 quad-lanes of each sample. No other barriers.
// ---------------------------------------------------------------------------
template<int TAB8>
__global__ __launch_bounds__(256, 4) void main_kernel(
    const int*   __restrict__ route_idx,
    const int*   __restrict__ time_idx,
    const float* __restrict__ route_table,
    const float* __restrict__ time_table,
    const float* __restrict__ mode_bias,
    const float* __restrict__ fc_w,
    const float* __restrict__ fc_b,
    const uint8_t* __restrict__ ws,
    float* __restrict__ out)
{
  __shared__ uint4 wlds[1792];                    // 28672 B fp8 w fragments
  const int tid  = threadIdx.x;
  const int wave = tid >> 6, lane = tid & 63;
  const int col  = lane & 15, quad = lane >> 4;
  const int m0   = blockIdx.x * 64 + wave * 16;
  const size_t ri = (size_t)route_idx[m0 + col];  // this lane's sample
  const size_t ti = (size_t)time_idx[m0 + col];

  // ---- early independent loads (overlap LDS fill latency) ----
  uint4 rw[4], tw[4];                             // this lane's 64B of r and t
  if (TAB8) {
    const uint8_t* rb = ws + WS_RT8_OFF + ri * 256 + quad * 16;
    const uint8_t* tb = ws + WS_TT8_OFF + ti * 256 + quad * 16;
    #pragma unroll
    for (int i = 0; i < 4; ++i) {
      rw[i] = *(const uint4*)(rb + i * 64);
      tw[i] = *(const uint4*)(tb + i * 64);
    }
  }
  const float* rap = (const float*)(ws + WS_RA_OFF) + ri * 8;
  const float* tbp = (const float*)(ws + WS_TB_OFF) + ti * 8;
  f32x4 ra0 = *(const f32x4*)rap; float ra4 = rap[4];
  f32x4 tb0 = *(const f32x4*)tbp; float tb4 = tbp[4];

  // ---- stage w fragments into LDS (coalesced, once per block) ----
  {
    const uint4* wsrc = (const uint4*)ws;
    #pragma unroll
    for (int j = 0; j < 7; ++j)
      wlds[j * 256 + tid] = wsrc[j * 256 + tid];
  }
  __syncthreads();

  float fcw_l[NTILES];                            // fc_w with the 1/64 x-scale
  #pragma unroll
  for (int nt = 0; nt < NTILES; ++nt) {
    const int n = nt * 16 + col;
    fcw_l[nt] = (n < KOUT) ? fc_w[n] * 0.015625f : 0.0f;
  }

  f32x4 acc[NTILES];
  #pragma unroll
  for (int nt = 0; nt < NTILES; ++nt) acc[nt] = (f32x4){0.f, 0.f, 0.f, 0.f};
  const uint2* wl2 = (const uint2*)wlds;

  #pragma unroll
  for (int ks = 0; ks < 8; ++ks) {
    uint32_t p0, p1;
    if (TAB8) {
      const int i = ks >> 1;
      const uint32_t ra = (ks & 1) ? rw[i].z : rw[i].x;
      const uint32_t rb = (ks & 1) ? rw[i].w : rw[i].y;
      const uint32_t ta = (ks & 1) ? tw[i].z : tw[i].x;
      const uint32_t tb = (ks & 1) ? tw[i].w : tw[i].y;
      f32x2 r01 = __builtin_amdgcn_cvt_pk_f32_fp8(ra, false);
      f32x2 r23 = __builtin_amdgcn_cvt_pk_f32_fp8(ra, true);
      f32x2 r45 = __builtin_amdgcn_cvt_pk_f32_fp8(rb, false);
      f32x2 r67 = __builtin_amdgcn_cvt_pk_f32_fp8(rb, true);
      f32x2 t01 = __builtin_amdgcn_cvt_pk_f32_fp8(ta, false);
      f32x2 t23 = __builtin_amdgcn_cvt_pk_f32_fp8(ta, true);
      f32x2 t45 = __builtin_amdgcn_cvt_pk_f32_fp8(tb, false);
      f32x2 t67 = __builtin_amdgcn_cvt_pk_f32_fp8(tb, true);
      f32x2 x01 = r01 * t01, x23 = r23 * t23, x45 = r45 * t45, x67 = r67 * t67;
      p0 = 0; p1 = 0;
      p0 = __builtin_amdgcn_cvt_pk_fp8_f32(x01.x, x01.y, p0, false);
      p0 = __builtin_amdgcn_cvt_pk_fp8_f32(x23.x, x23.y, p0, true);
      p1 = __builtin_amdgcn_cvt_pk_fp8_f32(x45.x, x45.y, p1, false);
      p1 = __builtin_amdgcn_cvt_pk_fp8_f32(x67.x, x67.y, p1, true);
    } else {
      const float4* rp = (const float4*)(route_table + ri * DIM + ks * 32 + quad * 8);
      const float4* tp = (const float4*)(time_table  + ti * DIM + ks * 32 + quad * 8);
      float4 r0 = rp[0], r1 = rp[1], t0 = tp[0], t1 = tp[1];
      p0 = 0; p1 = 0;
      p0 = __builtin_amdgcn_cvt_pk_fp8_f32(64.f * r0.x * t0.x, 64.f * r0.y * t0.y, p0, false);
      p0 = __builtin_amdgcn_cvt_pk_fp8_f32(64.f * r0.z * t0.z, 64.f * r0.w * t0.w, p0, true);
      p1 = __builtin_amdgcn_cvt_pk_fp8_f32(64.f * r1.x * t1.x, 64.f * r1.y * t1.y, p1, false);
      p1 = __builtin_amdgcn_cvt_pk_fp8_f32(64.f * r1.z * t1.z, 64.f * r1.w * t1.w, p1, true);
    }
    const long a64 = __builtin_bit_cast(long, make_uint2(p0, p1));
    #pragma unroll
    for (int nt = 0; nt < NTILES; ++nt) {
      const long b64 = __builtin_bit_cast(long, wl2[(ks * NTILES + nt) * 64 + lane]);
      acc[nt] = __builtin_amdgcn_mfma_f32_16x16x32_fp8_fp8(a64, b64, acc[nt], 0, 0, 0);
    }
  }

  // ---- relu-dot with fc_w, reduced across the 16 col-lanes via DPP ----
  float s[4];
  #pragma unroll
  for (int reg = 0; reg < 4; ++reg) {
    float v = 0.f;
    #pragma unroll
    for (int nt = 0; nt < NTILES; ++nt)
      v += fmaxf(acc[nt][reg], 0.f) * fcw_l[nt];
    s[reg] = sum16_all(v);                        // all 16 lanes get row sums
  }

  // ---- sigmoid tail, distributed over the 4 quad-lanes of each sample ----
  // quad q computes bias row i=q (j=0..4) + row-4 term j=q; quad0 also (4,4).
  const float rav[5] = {ra0.x, ra0.y, ra0.z, ra0.w, ra4};
  const float tbv[5] = {tb0.x, tb0.y, tb0.z, tb0.w, tb4};
  const float rq = (quad & 2) ? ((quad & 1) ? rav[3] : rav[2])
                              : ((quad & 1) ? rav[1] : rav[0]);
  const float tq = (quad & 2) ? ((quad & 1) ? tbv[3] : tbv[2])
                              : ((quad & 1) ? tbv[1] : tbv[0]);
  float sig = 0.f;
  #pragma unroll
  for (int j = 0; j < 5; ++j)
    sig += sigm(rq * tbv[j] + mode_bias[5 * quad + j]) * fc_w[KOUT + 5 * quad + j];
  sig += sigm(rav[4] * tq + mode_bias[20 + quad]) * fc_w[KOUT + 20 + quad];
  if (quad == 0)
    sig += sigm(rav[4] * tbv[4] + mode_bias[24]) * fc_w[KOUT + 24];
  sig += __shfl_xor(sig, 16, 64);
  sig += __shfl_xor(sig, 32, 64);                 // all 4 quad-lanes: full sum

  // ---- designated lane (holds this sample's gcp row) writes out ----
  if (quad == (col >> 2)) {
    const float sa = (col & 1) ? s[1] : s[0];
    const float sb = (col & 1) ? s[3] : s[2];
    const float gcp = (col & 2) ? sb : sa;
    out[m0 + col] = fc_b[0] + gcp + sig;
  }
}

// ---------------------------------------------------------------------------
extern "C" void kernel_launch(void* const* d_in, const int* in_sizes, int n_in,
                              void* d_out, int out_size, void* d_ws, size_t ws_size,
                              hipStream_t stream)
{
  const int*   route_idx   = (const int*)d_in[0];
  const int*   time_idx    = (const int*)d_in[1];
  const float* route_table = (const float*)d_in[2];
  const float* time_table  = (const float*)d_in[3];
  const float* w           = (const float*)d_in[4];
  const float* mode_a      = (const float*)d_in[5];
  const float* mode_b      = (const float*)d_in[6];
  const float* mode_bias   = (const float*)d_in[7];
  const float* fc_w        = (const float*)d_in[8];
  const float* fc_b        = (const float*)d_in[9];
  uint8_t* ws  = (uint8_t*)d_ws;
  float*   out = (float*)d_out;

  const int big = (ws_size >= WS_NEED) ? 1 : 0;   // constant across calls

  // 14 (w frags) + 126 (time rows) + 6250 (route rows)
  prep_kernel<<<6390, 256, 0, stream>>>(route_table, time_table, w,
                                        mode_a, mode_b, ws, big);
  if (big)
    main_kernel<1><<<BATCH / 64, 256, 0, stream>>>(route_idx, time_idx,
                                                   route_table, time_table,
                                                   mode_bias, fc_w, fc_b, ws, out);
  else
    main_kernel<0><<<BATCH / 64, 256, 0, stream>>>(route_idx, time_idx,
                                                   route_table, time_table,
                                                   mode_bias, fc_w, fc_b, ws, out);
}

// Round 5
// 202.985 us; speedup vs baseline: 1.3907x; 1.0016x over previous
//
#include <hip/hip_runtime.h>
#include <stdint.h>

#define BATCH   262144
#define NROUTES 100000
#define NTIME   2016
#define DIM     256
#define KOUT    100
#define NTILES  7          // 112 padded output cols / 16

typedef __attribute__((ext_vector_type(2))) float f32x2;
typedef __attribute__((ext_vector_type(4))) float f32x4;

// ---- workspace layout ----
#define WS_WFRAG_BYTES ((size_t)(NTILES * 8 * 64 * 8))      // 28672 B fp8 w frags
#define WS_RA_OFF   (WS_WFRAG_BYTES)                        // f32 [NROUTES][8]
#define WS_TB_OFF   (WS_RA_OFF + (size_t)NROUTES * 32)      // f32 [NTIME][8]
#define WS_RT8_OFF  (WS_TB_OFF + (size_t)NTIME * 32)        // fp8 [NROUTES][256] permuted
#define WS_TT8_OFF  (WS_RT8_OFF + (size_t)NROUTES * 256)    // fp8 [NTIME][256] permuted
#define WS_NEED     (WS_TT8_OFF + (size_t)NTIME * 256)      // ~29.4 MB

// fused DPP lane-shift + add (pure VALU, no LDS)
template<int CTRL>
static __device__ __forceinline__ float dpp_add(float x) {
  int s = __builtin_amdgcn_update_dpp(0, __builtin_bit_cast(int, x), CTRL, 0xF, 0xF, true);
  return x + __builtin_bit_cast(float, s);
}
// full 64-lane sum -> lane 63
static __device__ __forceinline__ float wave_sum63(float x) {
  x = dpp_add<0x111>(x);  // row_shr:1
  x = dpp_add<0x112>(x);  // row_shr:2
  x = dpp_add<0x114>(x);  // row_shr:4
  x = dpp_add<0x118>(x);  // row_shr:8
  x = dpp_add<0x142>(x);  // row_bcast:15
  x = dpp_add<0x143>(x);  // row_bcast:31
  return x;
}
// 16-lane-group sum, broadcast to all 16 lanes
static __device__ __forceinline__ float sum16_all(float x) {
  x = dpp_add<0x0B1>(x);  // quad_perm [1,0,3,2]
  x = dpp_add<0x04E>(x);  // quad_perm [2,3,0,1]
  x = dpp_add<0x124>(x);  // row_ror:4
  x = dpp_add<0x128>(x);  // row_ror:8
  return x;
}
static __device__ __forceinline__ float sigm(float z) {
  return __builtin_amdgcn_rcpf(1.0f + __expf(-z));
}

// ---------------------------------------------------------------------------
// Prep: (1) w -> fp8 B-frag order (b<14), zero-padded cols 100..111
//       (2) TB + fp8 time table   (126 blocks, 16 rows)
//       (3) RA + fp8 route table  (6250 blocks, 16 rows)
// fp8 rows PERMUTED: logical k -> phys (ks>>1)*64 + quad*16 + (ks&1)*8 + j
// with ks=k>>5, quad=(k>>3)&3, j=k&7.  Values scaled x8.
// ---------------------------------------------------------------------------
__global__ __launch_bounds__(256) void prep_kernel(
    const float* __restrict__ route_table,
    const float* __restrict__ time_table,
    const float* __restrict__ w,
    const float* __restrict__ mode_a,
    const float* __restrict__ mode_b,
    uint8_t* __restrict__ ws, int do8)
{
  const int b   = blockIdx.x;
  const int tid = threadIdx.x;

  if (b < 14) {                                   // ---- w fragments (fp8) ----
    const int u = b * 256 + tid;                  // [0, 3584)
    const int lane = u & 63;
    const int frag = u >> 6;                      // ks*7 + nt
    const int ks = frag / NTILES;
    const int nt = frag % NTILES;
    const int n  = nt * 16 + (lane & 15);
    const int k0 = ks * 32 + (lane >> 4) * 8;
    float v[8];
    #pragma unroll
    for (int j = 0; j < 8; ++j)
      v[j] = (n < KOUT) ? w[(size_t)(k0 + j) * KOUT + n] : 0.0f;
    uint32_t d0 = 0, d1 = 0;
    d0 = __builtin_amdgcn_cvt_pk_fp8_f32(v[0], v[1], d0, false);
    d0 = __builtin_amdgcn_cvt_pk_fp8_f32(v[2], v[3], d0, true);
    d1 = __builtin_amdgcn_cvt_pk_fp8_f32(v[4], v[5], d1, false);
    d1 = __builtin_amdgcn_cvt_pk_fp8_f32(v[6], v[7], d1, true);
    ((uint2*)ws)[u] = make_uint2(d0, d1);
    return;
  }

  const float* tab; const float* proj; float* outp; uint8_t* out8; int base;
  if (b < 14 + 126) {
    tab = time_table;  proj = mode_b; outp = (float*)(ws + WS_TB_OFF);
    out8 = ws + WS_TT8_OFF; base = (b - 14) * 16;
  } else {
    tab = route_table; proj = mode_a; outp = (float*)(ws + WS_RA_OFF);
    out8 = ws + WS_RT8_OFF; base = (b - 140) * 16;
  }

  const int wave = tid >> 6, lane = tid & 63;
  float A[4][5];                                  // proj rows 4*lane..4*lane+3
  #pragma unroll
  for (int j = 0; j < 4; ++j)
    #pragma unroll
    for (int i = 0; i < 5; ++i)
      A[j][i] = proj[(4 * lane + j) * 5 + i];

  // phys offset of this lane's 4 fp8 bytes (logical k = 4*lane..4*lane+3)
  const int p0 = (lane >> 4) * 64 + ((lane >> 1) & 3) * 16 +
                 ((lane >> 3) & 1) * 8 + (lane & 1) * 4;

  const int row0 = base + wave * 4;               // 4 rows per wave
  float4 v[4];
  #pragma unroll
  for (int rr = 0; rr < 4; ++rr)
    v[rr] = *(const float4*)(tab + (size_t)(row0 + rr) * DIM + 4 * lane);

  #pragma unroll
  for (int rr = 0; rr < 4; ++rr) {
    const int row = row0 + rr;
    if (do8) {                                    // fp8 emission, scaled x8
      uint32_t u = 0;
      u = __builtin_amdgcn_cvt_pk_fp8_f32(8.f * v[rr].x, 8.f * v[rr].y, u, false);
      u = __builtin_amdgcn_cvt_pk_fp8_f32(8.f * v[rr].z, 8.f * v[rr].w, u, true);
      *(uint32_t*)(out8 + (size_t)row * 256 + p0) = u;
    }
    float p[5];
    #pragma unroll
    for (int i = 0; i < 5; ++i) {
      float s = v[rr].x * A[0][i] + v[rr].y * A[1][i] + v[rr].z * A[2][i] + v[rr].w * A[3][i];
      p[i] = wave_sum63(s);
    }
    if (lane == 63) {
      float* o = outp + (size_t)row * 8;
      *(f32x4*)o = (f32x4){p[0], p[1], p[2], p[3]};
      o[4] = p[4];
    }
  }
}

// ---------------------------------------------------------------------------
// Main (fp8 path): each wave owns 4 consecutive 16-sample tiles, software-
// pipelined: while tile i's K-loop runs, tile i+1's gathers are in flight
// and tile i+2's indices are loading. w frags staged in LDS once per block.
// ---------------------------------------------------------------------------
__global__ __launch_bounds__(256, 2) void main_pipelined(
    const int*   __restrict__ route_idx,
    const int*   __restrict__ time_idx,
    const float* __restrict__ mode_bias,
    const float* __restrict__ fc_w,
    const float* __restrict__ fc_b,
    const uint8_t* __restrict__ ws,
    float* __restrict__ out)
{
  __shared__ uint4 wlds[1792];                    // 28672 B fp8 w fragments
  const int tid  = threadIdx.x;
  const int wave = tid >> 6, lane = tid & 63;
  const int col  = lane & 15, quad = lane >> 4;
  const int base = (blockIdx.x * 4 + wave) * 64;  // 4 tiles x 16 samples

  // ---- stage w fragments into LDS (coalesced, once per block) ----
  {
    const uint4* wsrc = (const uint4*)ws;
    #pragma unroll
    for (int j = 0; j < 7; ++j)
      wlds[j * 256 + tid] = wsrc[j * 256 + tid];
  }

  float fcw_l[NTILES];                            // fc_w with the 1/64 x-scale
  #pragma unroll
  for (int nt = 0; nt < NTILES; ++nt) {
    const int n = nt * 16 + col;
    fcw_l[nt] = (n < KOUT) ? fc_w[n] * 0.015625f : 0.0f;
  }
  const float fb = fc_b[0];

  // ---- pipeline state: double-buffered gathers ----
  uint4 rw[2][4], tw[2][4];
  f32x4 ra0[2], tb0[2];
  float ra4[2], tb4[2];

  auto issue = [&](int buf, int ri, int ti) {
    const uint8_t* rb = ws + WS_RT8_OFF + (size_t)ri * 256 + quad * 16;
    const uint8_t* tb = ws + WS_TT8_OFF + (size_t)ti * 256 + quad * 16;
    #pragma unroll
    for (int i = 0; i < 4; ++i) {
      rw[buf][i] = *(const uint4*)(rb + i * 64);
      tw[buf][i] = *(const uint4*)(tb + i * 64);
    }
    const float* rap = (const float*)(ws + WS_RA_OFF) + (size_t)ri * 8;
    const float* tbp = (const float*)(ws + WS_TB_OFF) + (size_t)ti * 8;
    ra0[buf] = *(const f32x4*)rap; ra4[buf] = rap[4];
    tb0[buf] = *(const f32x4*)tbp; tb4[buf] = tbp[4];
  };

  // prologue: tile0 idx -> tile0 gathers; tile1 idx
  int ri_n = route_idx[base + col];
  int ti_n = time_idx[base + col];
  issue(0, ri_n, ti_n);
  ri_n = route_idx[base + 16 + col];
  ti_n = time_idx[base + 16 + col];

  __syncthreads();                                // wlds ready

  const uint2* wl2 = (const uint2*)wlds;

  #pragma unroll
  for (int it = 0; it < 4; ++it) {
    const int cb = it & 1, nb = cb ^ 1;
    if (it < 3) {
      issue(nb, ri_n, ti_n);                      // tile it+1 gathers in flight
      if (it < 2) {
        ri_n = route_idx[base + (it + 2) * 16 + col];
        ti_n = time_idx[base + (it + 2) * 16 + col];
      }
    }

    // ---- K-loop on buffer cb ----
    f32x4 acc[NTILES];
    #pragma unroll
    for (int nt = 0; nt < NTILES; ++nt) acc[nt] = (f32x4){0.f, 0.f, 0.f, 0.f};

    #pragma unroll
    for (int ks = 0; ks < 8; ++ks) {
      const int i = ks >> 1;
      const uint32_t ra = (ks & 1) ? rw[cb][i].z : rw[cb][i].x;
      const uint32_t rb = (ks & 1) ? rw[cb][i].w : rw[cb][i].y;
      const uint32_t ta = (ks & 1) ? tw[cb][i].z : tw[cb][i].x;
      const uint32_t tb = (ks & 1) ? tw[cb][i].w : tw[cb][i].y;
      f32x2 r01 = __builtin_amdgcn_cvt_pk_f32_fp8(ra, false);
      f32x2 r23 = __builtin_amdgcn_cvt_pk_f32_fp8(ra, true);
      f32x2 r45 = __builtin_amdgcn_cvt_pk_f32_fp8(rb, false);
      f32x2 r67 = __builtin_amdgcn_cvt_pk_f32_fp8(rb, true);
      f32x2 t01 = __builtin_amdgcn_cvt_pk_f32_fp8(ta, false);
      f32x2 t23 = __builtin_amdgcn_cvt_pk_f32_fp8(ta, true);
      f32x2 t45 = __builtin_amdgcn_cvt_pk_f32_fp8(tb, false);
      f32x2 t67 = __builtin_amdgcn_cvt_pk_f32_fp8(tb, true);
      f32x2 x01 = r01 * t01, x23 = r23 * t23, x45 = r45 * t45, x67 = r67 * t67;
      uint32_t p0 = 0, p1 = 0;
      p0 = __builtin_amdgcn_cvt_pk_fp8_f32(x01.x, x01.y, p0, false);
      p0 = __builtin_amdgcn_cvt_pk_fp8_f32(x23.x, x23.y, p0, true);
      p1 = __builtin_amdgcn_cvt_pk_fp8_f32(x45.x, x45.y, p1, false);
      p1 = __builtin_amdgcn_cvt_pk_fp8_f32(x67.x, x67.y, p1, true);
      const long a64 = __builtin_bit_cast(long, make_uint2(p0, p1));
      #pragma unroll
      for (int nt = 0; nt < NTILES; ++nt) {
        const long b64 = __builtin_bit_cast(long, wl2[(ks * NTILES + nt) * 64 + lane]);
        acc[nt] = __builtin_amdgcn_mfma_f32_16x16x32_fp8_fp8(a64, b64, acc[nt], 0, 0, 0);
      }
    }

    // ---- relu-dot with fc_w, reduced across the 16 col-lanes via DPP ----
    float s[4];
    #pragma unroll
    for (int reg = 0; reg < 4; ++reg) {
      float v = 0.f;
      #pragma unroll
      for (int nt = 0; nt < NTILES; ++nt)
        v += fmaxf(acc[nt][reg], 0.f) * fcw_l[nt];
      s[reg] = sum16_all(v);
    }

    // ---- sigmoid tail, distributed over the 4 quad-lanes of each sample ----
    const float rav[5] = {ra0[cb].x, ra0[cb].y, ra0[cb].z, ra0[cb].w, ra4[cb]};
    const float tbv[5] = {tb0[cb].x, tb0[cb].y, tb0[cb].z, tb0[cb].w, tb4[cb]};
    const float rq = (quad & 2) ? ((quad & 1) ? rav[3] : rav[2])
                                : ((quad & 1) ? rav[1] : rav[0]);
    const float tq = (quad & 2) ? ((quad & 1) ? tbv[3] : tbv[2])
                                : ((quad & 1) ? tbv[1] : tbv[0]);
    float sig = 0.f;
    #pragma unroll
    for (int j = 0; j < 5; ++j)
      sig += sigm(rq * tbv[j] + mode_bias[5 * quad + j]) * fc_w[KOUT + 5 * quad + j];
    sig += sigm(rav[4] * tq + mode_bias[20 + quad]) * fc_w[KOUT + 20 + quad];
    if (quad == 0)
      sig += sigm(rav[4] * tbv[4] + mode_bias[24]) * fc_w[KOUT + 24];
    sig += __shfl_xor(sig, 16, 64);
    sig += __shfl_xor(sig, 32, 64);

    if (quad == (col >> 2)) {
      const float sa = (col & 1) ? s[1] : s[0];
      const float sb = (col & 1) ? s[3] : s[2];
      const float gcp = (col & 2) ? sb : sa;
      out[base + it * 16 + col] = fb + gcp + sig;
    }
  }
}

// ---------------------------------------------------------------------------
// Fallback (small ws): one tile per wave, gather f32 tables directly.
// ---------------------------------------------------------------------------
__global__ __launch_bounds__(256, 4) void main_fallback(
    const int*   __restrict__ route_idx,
    const int*   __restrict__ time_idx,
    const float* __restrict__ route_table,
    const float* __restrict__ time_table,
    const float* __restrict__ mode_bias,
    const float* __restrict__ fc_w,
    const float* __restrict__ fc_b,
    const uint8_t* __restrict__ ws,
    float* __restrict__ out)
{
  __shared__ uint4 wlds[1792];
  const int tid  = threadIdx.x;
  const int wave = tid >> 6, lane = tid & 63;
  const int col  = lane & 15, quad = lane >> 4;
  const int m0   = blockIdx.x * 64 + wave * 16;
  const size_t ri = (size_t)route_idx[m0 + col];
  const size_t ti = (size_t)time_idx[m0 + col];

  const float* rap = (const float*)(ws + WS_RA_OFF) + ri * 8;
  const float* tbp = (const float*)(ws + WS_TB_OFF) + ti * 8;
  f32x4 ra0 = *(const f32x4*)rap; float ra4 = rap[4];
  f32x4 tb0 = *(const f32x4*)tbp; float tb4 = tbp[4];

  {
    const uint4* wsrc = (const uint4*)ws;
    #pragma unroll
    for (int j = 0; j < 7; ++j)
      wlds[j * 256 + tid] = wsrc[j * 256 + tid];
  }
  __syncthreads();

  float fcw_l[NTILES];
  #pragma unroll
  for (int nt = 0; nt < NTILES; ++nt) {
    const int n = nt * 16 + col;
    fcw_l[nt] = (n < KOUT) ? fc_w[n] * 0.015625f : 0.0f;
  }

  f32x4 acc[NTILES];
  #pragma unroll
  for (int nt = 0; nt < NTILES; ++nt) acc[nt] = (f32x4){0.f, 0.f, 0.f, 0.f};
  const uint2* wl2 = (const uint2*)wlds;

  #pragma unroll
  for (int ks = 0; ks < 8; ++ks) {
    const float4* rp = (const float4*)(route_table + ri * DIM + ks * 32 + quad * 8);
    const float4* tp = (const float4*)(time_table  + ti * DIM + ks * 32 + quad * 8);
    float4 r0 = rp[0], r1 = rp[1], t0 = tp[0], t1 = tp[1];
    uint32_t p0 = 0, p1 = 0;
    p0 = __builtin_amdgcn_cvt_pk_fp8_f32(64.f * r0.x * t0.x, 64.f * r0.y * t0.y, p0, false);
    p0 = __builtin_amdgcn_cvt_pk_fp8_f32(64.f * r0.z * t0.z, 64.f * r0.w * t0.w, p0, true);
    p1 = __builtin_amdgcn_cvt_pk_fp8_f32(64.f * r1.x * t1.x, 64.f * r1.y * t1.y, p1, false);
    p1 = __builtin_amdgcn_cvt_pk_fp8_f32(64.f * r1.z * t1.z, 64.f * r1.w * t1.w, p1, true);
    const long a64 = __builtin_bit_cast(long, make_uint2(p0, p1));
    #pragma unroll
    for (int nt = 0; nt < NTILES; ++nt) {
      const long b64 = __builtin_bit_cast(long, wl2[(ks * NTILES + nt) * 64 + lane]);
      acc[nt] = __builtin_amdgcn_mfma_f32_16x16x32_fp8_fp8(a64, b64, acc[nt], 0, 0, 0);
    }
  }

  float s[4];
  #pragma unroll
  for (int reg = 0; reg < 4; ++reg) {
    float v = 0.f;
    #pragma unroll
    for (int nt = 0; nt < NTILES; ++nt)
      v += fmaxf(acc[nt][reg], 0.f) * fcw_l[nt];
    s[reg] = sum16_all(v);
  }

  const float rav[5] = {ra0.x, ra0.y, ra0.z, ra0.w, ra4};
  const float tbv[5] = {tb0.x, tb0.y, tb0.z, tb0.w, tb4};
  const float rq = (quad & 2) ? ((quad & 1) ? rav[3] : rav[2])
                              : ((quad & 1) ? rav[1] : rav[0]);
  const float tq = (quad & 2) ? ((quad & 1) ? tbv[3] : tbv[2])
                              : ((quad & 1) ? tbv[1] : tbv[0]);
  float sig = 0.f;
  #pragma unroll
  for (int j = 0; j < 5; ++j)
    sig += sigm(rq * tbv[j] + mode_bias[5 * quad + j]) * fc_w[KOUT + 5 * quad + j];
  sig += sigm(rav[4] * tq + mode_bias[20 + quad]) * fc_w[KOUT + 20 + quad];
  if (quad == 0)
    sig += sigm(rav[4] * tbv[4] + mode_bias[24]) * fc_w[KOUT + 24];
  sig += __shfl_xor(sig, 16, 64);
  sig += __shfl_xor(sig, 32, 64);

  if (quad == (col >> 2)) {
    const float sa = (col & 1) ? s[1] : s[0];
    const float sb = (col & 1) ? s[3] : s[2];
    const float gcp = (col & 2) ? sb : sa;
    out[m0 + col] = fc_b[0] + gcp + sig;
  }
}

// ---------------------------------------------------------------------------
extern "C" void kernel_launch(void* const* d_in, const int* in_sizes, int n_in,
                              void* d_out, int out_size, void* d_ws, size_t ws_size,
                              hipStream_t stream)
{
  const int*   route_idx   = (const int*)d_in[0];
  const int*   time_idx    = (const int*)d_in[1];
  const float* route_table = (const float*)d_in[2];
  const float* time_table  = (const float*)d_in[3];
  const float* w           = (const float*)d_in[4];
  const float* mode_a      = (const float*)d_in[5];
  const float* mode_b      = (const float*)d_in[6];
  const float* mode_bias   = (const float*)d_in[7];
  const float* fc_w        = (const float*)d_in[8];
  const float* fc_b        = (const float*)d_in[9];
  uint8_t* ws  = (uint8_t*)d_ws;
  float*   out = (float*)d_out;

  const int big = (ws_size >= WS_NEED) ? 1 : 0;   // constant across calls

  // 14 (w frags) + 126 (time rows) + 6250 (route rows)
  prep_kernel<<<6390, 256, 0, stream>>>(route_table, time_table, w,
                                        mode_a, mode_b, ws, big);
  if (big)
    main_pipelined<<<BATCH / 256, 256, 0, stream>>>(route_idx, time_idx,
                                                    mode_bias, fc_w, fc_b, ws, out);
  else
    main_fallback<<<BATCH / 64, 256, 0, stream>>>(route_idx, time_idx,
                                                  route_table, time_table,
                                                  mode_bias, fc_w, fc_b, ws, out);
}

// Round 6
// 201.902 us; speedup vs baseline: 1.3981x; 1.0054x over previous
//
#include <hip/hip_runtime.h>
#include <stdint.h>

#define BATCH   262144
#define NROUTES 100000
#define NTIME   2016
#define DIM     256
#define KOUT    100
#define NTILES  7          // 112 padded output cols / 16

typedef __attribute__((ext_vector_type(2))) float f32x2;
typedef __attribute__((ext_vector_type(4))) float f32x4;

// ---- workspace layout ----
#define WS_WFRAG_BYTES ((size_t)(NTILES * 8 * 64 * 8))      // 28672 B fp8 w frags
#define WS_RA_OFF   (WS_WFRAG_BYTES)                        // f32 [NROUTES][8]
#define WS_TB_OFF   (WS_RA_OFF + (size_t)NROUTES * 32)      // f32 [NTIME][8]
#define WS_RT8_OFF  (WS_TB_OFF + (size_t)NTIME * 32)        // fp8 [NROUTES][256] permuted
#define WS_TT8_OFF  (WS_RT8_OFF + (size_t)NROUTES * 256)    // fp8 [NTIME][256] permuted
#define WS_NEED     (WS_TT8_OFF + (size_t)NTIME * 256)      // ~29.4 MB

// fused DPP lane-shift + add (pure VALU, no LDS)
template<int CTRL>
static __device__ __forceinline__ float dpp_add(float x) {
  int s = __builtin_amdgcn_update_dpp(0, __builtin_bit_cast(int, x), CTRL, 0xF, 0xF, true);
  return x + __builtin_bit_cast(float, s);
}
// full 64-lane sum -> lane 63
static __device__ __forceinline__ float wave_sum63(float x) {
  x = dpp_add<0x111>(x);  // row_shr:1
  x = dpp_add<0x112>(x);  // row_shr:2
  x = dpp_add<0x114>(x);  // row_shr:4
  x = dpp_add<0x118>(x);  // row_shr:8
  x = dpp_add<0x142>(x);  // row_bcast:15
  x = dpp_add<0x143>(x);  // row_bcast:31
  return x;
}
// 16-lane-group sum, broadcast to all 16 lanes
static __device__ __forceinline__ float sum16_all(float x) {
  x = dpp_add<0x0B1>(x);  // quad_perm [1,0,3,2]
  x = dpp_add<0x04E>(x);  // quad_perm [2,3,0,1]
  x = dpp_add<0x124>(x);  // row_ror:4
  x = dpp_add<0x128>(x);  // row_ror:8
  return x;
}
static __device__ __forceinline__ float sigm(float z) {
  return __builtin_amdgcn_rcpf(1.0f + __expf(-z));
}

// ---------------------------------------------------------------------------
// Prep: (1) w -> fp8 B-frag order (b<14), zero-padded cols 100..111
//       (2) TB + fp8 time table   (63 blocks, 32 rows)
//       (3) RA + fp8 route table  (3125 blocks, 32 rows)
// fp8 rows PERMUTED: logical k -> phys (ks>>1)*64 + quad*16 + (ks&1)*8 + j.
// We permute the LOAD side (lane l reads logical dword perm(l)) so the fp8
// store is a linear coalesced dword at byte 4*l.  Values scaled x8.
// ---------------------------------------------------------------------------
template<int DO8>
__global__ __launch_bounds__(256) void prep_kernel(
    const float* __restrict__ route_table,
    const float* __restrict__ time_table,
    const float* __restrict__ w,
    const float* __restrict__ mode_a,
    const float* __restrict__ mode_b,
    uint8_t* __restrict__ ws)
{
  const int b   = blockIdx.x;
  const int tid = threadIdx.x;

  if (b < 14) {                                   // ---- w fragments (fp8) ----
    const int u = b * 256 + tid;                  // [0, 3584)
    const int lane = u & 63;
    const int frag = u >> 6;                      // ks*7 + nt
    const int ks = frag / NTILES;
    const int nt = frag % NTILES;
    const int n  = nt * 16 + (lane & 15);
    const int k0 = ks * 32 + (lane >> 4) * 8;
    float v[8];
    #pragma unroll
    for (int j = 0; j < 8; ++j)
      v[j] = (n < KOUT) ? w[(size_t)(k0 + j) * KOUT + n] : 0.0f;
    uint32_t d0 = 0, d1 = 0;
    d0 = __builtin_amdgcn_cvt_pk_fp8_f32(v[0], v[1], d0, false);
    d0 = __builtin_amdgcn_cvt_pk_fp8_f32(v[2], v[3], d0, true);
    d1 = __builtin_amdgcn_cvt_pk_fp8_f32(v[4], v[5], d1, false);
    d1 = __builtin_amdgcn_cvt_pk_fp8_f32(v[6], v[7], d1, true);
    ((uint2*)ws)[u] = make_uint2(d0, d1);
    return;
  }

  const float* tab; const float* proj; float* outp; uint8_t* out8; int base;
  if (b < 14 + 63) {
    tab = time_table;  proj = mode_b; outp = (float*)(ws + WS_TB_OFF);
    out8 = ws + WS_TT8_OFF; base = (b - 14) * 32;
  } else {
    tab = route_table; proj = mode_a; outp = (float*)(ws + WS_RA_OFF);
    out8 = ws + WS_RT8_OFF; base = (b - 77) * 32;
  }

  const int wave = tid >> 6, lane = tid & 63;
  // inverse fragment permutation: lane l owns logical dword perm(l)
  const int perm = (2 * (lane >> 4) + ((lane >> 1) & 1)) * 8 +
                   ((lane >> 2) & 3) * 2 + (lane & 1);

  float A[4][5];                                  // proj rows 4*perm..4*perm+3
  #pragma unroll
  for (int j = 0; j < 4; ++j)
    #pragma unroll
    for (int i = 0; i < 5; ++i)
      A[j][i] = proj[(4 * perm + j) * 5 + i];

  const int row0 = base + wave * 8;               // 8 rows per wave
  float4 v[8];
  #pragma unroll
  for (int rr = 0; rr < 8; ++rr)
    v[rr] = *(const float4*)(tab + (size_t)(row0 + rr) * DIM + 4 * perm);

  #pragma unroll
  for (int rr = 0; rr < 8; ++rr) {
    const int row = row0 + rr;
    if (DO8) {                                    // fp8 emission, scaled x8
      uint32_t u = 0;
      u = __builtin_amdgcn_cvt_pk_fp8_f32(8.f * v[rr].x, 8.f * v[rr].y, u, false);
      u = __builtin_amdgcn_cvt_pk_fp8_f32(8.f * v[rr].z, 8.f * v[rr].w, u, true);
      *(uint32_t*)(out8 + (size_t)row * 256 + 4 * lane) = u;   // coalesced
    }
    float p[5];
    #pragma unroll
    for (int i = 0; i < 5; ++i) {
      float s = v[rr].x * A[0][i] + v[rr].y * A[1][i] + v[rr].z * A[2][i] + v[rr].w * A[3][i];
      p[i] = wave_sum63(s);
    }
    if (lane == 63) {
      float* o = outp + (size_t)row * 8;
      *(f32x4*)o = (f32x4){p[0], p[1], p[2], p[3]};
      o[4] = p[4];
    }
  }
}

// ---------------------------------------------------------------------------
// Main (fp8 path): each wave owns 4 consecutive 16-sample tiles, software-
// pipelined. All 4 tile indices loaded up front; RA/TB for tile i prefetched
// BEFORE tile i+1's gathers so the epilogue wait doesn't drain the pipeline.
// w frags staged in LDS once per block.
// ---------------------------------------------------------------------------
__global__ __launch_bounds__(256, 3) void main_pipelined(
    const int*   __restrict__ route_idx,
    const int*   __restrict__ time_idx,
    const float* __restrict__ mode_bias,
    const float* __restrict__ fc_w,
    const float* __restrict__ fc_b,
    const uint8_t* __restrict__ ws,
    float* __restrict__ out)
{
  __shared__ uint4 wlds[1792];                    // 28672 B fp8 w fragments
  const int tid  = threadIdx.x;
  const int wave = tid >> 6, lane = tid & 63;
  const int col  = lane & 15, quad = lane >> 4;
  const int base = (blockIdx.x * 4 + wave) * 64;  // 4 tiles x 16 samples

  // ---- all tile indices up front (no mid-pipeline idx chains) ----
  int ri[4], ti[4];
  #pragma unroll
  for (int t = 0; t < 4; ++t) {
    ri[t] = route_idx[base + t * 16 + col];
    ti[t] = time_idx[base + t * 16 + col];
  }

  // ---- stage w fragments into LDS (coalesced, once per block) ----
  {
    const uint4* wsrc = (const uint4*)ws;
    #pragma unroll
    for (int j = 0; j < 7; ++j)
      wlds[j * 256 + tid] = wsrc[j * 256 + tid];
  }

  float fcw_l[NTILES];                            // fc_w with the 1/64 x-scale
  #pragma unroll
  for (int nt = 0; nt < NTILES; ++nt) {
    const int n = nt * 16 + col;
    fcw_l[nt] = (n < KOUT) ? fc_w[n] * 0.015625f : 0.0f;
  }
  const float fb = fc_b[0];

  uint4 rw[2][4], tw[2][4];                       // double-buffered gathers
  auto issue = [&](int buf, int t) {
    const uint8_t* rb = ws + WS_RT8_OFF + (size_t)ri[t] * 256 + quad * 16;
    const uint8_t* tb = ws + WS_TT8_OFF + (size_t)ti[t] * 256 + quad * 16;
    #pragma unroll
    for (int i = 0; i < 4; ++i) {
      rw[buf][i] = *(const uint4*)(rb + i * 64);
      tw[buf][i] = *(const uint4*)(tb + i * 64);
    }
  };

  issue(0, 0);                                    // tile0 gathers in flight
  __syncthreads();                                // wlds ready

  const uint2* wl2 = (const uint2*)wlds;

  #pragma unroll
  for (int it = 0; it < 4; ++it) {
    const int cb = it & 1, nb = cb ^ 1;

    // RA/TB for CURRENT tile first (oldest), then next tile's gathers —
    // epilogue's RA/TB wait leaves the next gathers in flight.
    const float* rap = (const float*)(ws + WS_RA_OFF) + (size_t)ri[it] * 8;
    const float* tbp = (const float*)(ws + WS_TB_OFF) + (size_t)ti[it] * 8;
    f32x4 ra0 = *(const f32x4*)rap; float ra4 = rap[4];
    f32x4 tb0 = *(const f32x4*)tbp; float tb4 = tbp[4];
    if (it < 3) issue(nb, it + 1);

    // ---- K-loop on buffer cb ----
    f32x4 acc[NTILES];
    #pragma unroll
    for (int nt = 0; nt < NTILES; ++nt) acc[nt] = (f32x4){0.f, 0.f, 0.f, 0.f};

    #pragma unroll
    for (int ks = 0; ks < 8; ++ks) {
      const int i = ks >> 1;
      const uint32_t ra = (ks & 1) ? rw[cb][i].z : rw[cb][i].x;
      const uint32_t rb = (ks & 1) ? rw[cb][i].w : rw[cb][i].y;
      const uint32_t ta = (ks & 1) ? tw[cb][i].z : tw[cb][i].x;
      const uint32_t tb = (ks & 1) ? tw[cb][i].w : tw[cb][i].y;
      f32x2 r01 = __builtin_amdgcn_cvt_pk_f32_fp8(ra, false);
      f32x2 r23 = __builtin_amdgcn_cvt_pk_f32_fp8(ra, true);
      f32x2 r45 = __builtin_amdgcn_cvt_pk_f32_fp8(rb, false);
      f32x2 r67 = __builtin_amdgcn_cvt_pk_f32_fp8(rb, true);
      f32x2 t01 = __builtin_amdgcn_cvt_pk_f32_fp8(ta, false);
      f32x2 t23 = __builtin_amdgcn_cvt_pk_f32_fp8(ta, true);
      f32x2 t45 = __builtin_amdgcn_cvt_pk_f32_fp8(tb, false);
      f32x2 t67 = __builtin_amdgcn_cvt_pk_f32_fp8(tb, true);
      f32x2 x01 = r01 * t01, x23 = r23 * t23, x45 = r45 * t45, x67 = r67 * t67;
      uint32_t p0 = 0, p1 = 0;
      p0 = __builtin_amdgcn_cvt_pk_fp8_f32(x01.x, x01.y, p0, false);
      p0 = __builtin_amdgcn_cvt_pk_fp8_f32(x23.x, x23.y, p0, true);
      p1 = __builtin_amdgcn_cvt_pk_fp8_f32(x45.x, x45.y, p1, false);
      p1 = __builtin_amdgcn_cvt_pk_fp8_f32(x67.x, x67.y, p1, true);
      const long a64 = __builtin_bit_cast(long, make_uint2(p0, p1));
      #pragma unroll
      for (int nt = 0; nt < NTILES; ++nt) {
        const long b64 = __builtin_bit_cast(long, wl2[(ks * NTILES + nt) * 64 + lane]);
        acc[nt] = __builtin_amdgcn_mfma_f32_16x16x32_fp8_fp8(a64, b64, acc[nt], 0, 0, 0);
      }
    }

    // ---- relu-dot with fc_w, reduced across the 16 col-lanes via DPP ----
    float s[4];
    #pragma unroll
    for (int reg = 0; reg < 4; ++reg) {
      float v = 0.f;
      #pragma unroll
      for (int nt = 0; nt < NTILES; ++nt)
        v += fmaxf(acc[nt][reg], 0.f) * fcw_l[nt];
      s[reg] = sum16_all(v);
    }

    // ---- sigmoid tail, distributed over the 4 quad-lanes of each sample ----
    const float rav[5] = {ra0.x, ra0.y, ra0.z, ra0.w, ra4};
    const float tbv[5] = {tb0.x, tb0.y, tb0.z, tb0.w, tb4};
    const float rq = (quad & 2) ? ((quad & 1) ? rav[3] : rav[2])
                                : ((quad & 1) ? rav[1] : rav[0]);
    const float tq = (quad & 2) ? ((quad & 1) ? tbv[3] : tbv[2])
                                : ((quad & 1) ? tbv[1] : tbv[0]);
    float sig = 0.f;
    #pragma unroll
    for (int j = 0; j < 5; ++j)
      sig += sigm(rq * tbv[j] + mode_bias[5 * quad + j]) * fc_w[KOUT + 5 * quad + j];
    sig += sigm(rav[4] * tq + mode_bias[20 + quad]) * fc_w[KOUT + 20 + quad];
    if (quad == 0)
      sig += sigm(rav[4] * tbv[4] + mode_bias[24]) * fc_w[KOUT + 24];
    sig += __shfl_xor(sig, 16, 64);
    sig += __shfl_xor(sig, 32, 64);

    if (quad == (col >> 2)) {
      const float sa = (col & 1) ? s[1] : s[0];
      const float sb = (col & 1) ? s[3] : s[2];
      const float gcp = (col & 2) ? sb : sa;
      out[base + it * 16 + col] = fb + gcp + sig;
    }
  }
}

// ---------------------------------------------------------------------------
// Fallback (small ws): one tile per wave, gather f32 tables directly.
// ---------------------------------------------------------------------------
__global__ __launch_bounds__(256, 4) void main_fallback(
    const int*   __restrict__ route_idx,
    const int*   __restrict__ time_idx,
    const float* __restrict__ route_table,
    const float* __restrict__ time_table,
    const float* __restrict__ mode_bias,
    const float* __restrict__ fc_w,
    const float* __restrict__ fc_b,
    const uint8_t* __restrict__ ws,
    float* __restrict__ out)
{
  __shared__ uint4 wlds[1792];
  const int tid  = threadIdx.x;
  const int wave = tid >> 6, lane = tid & 63;
  const int col  = lane & 15, quad = lane >> 4;
  const int m0   = blockIdx.x * 64 + wave * 16;
  const size_t ri = (size_t)route_idx[m0 + col];
  const size_t ti = (size_t)time_idx[m0 + col];

  const float* rap = (const float*)(ws + WS_RA_OFF) + ri * 8;
  const float* tbp = (const float*)(ws + WS_TB_OFF) + ti * 8;
  f32x4 ra0 = *(const f32x4*)rap; float ra4 = rap[4];
  f32x4 tb0 = *(const f32x4*)tbp; float tb4 = tbp[4];

  {
    const uint4* wsrc = (const uint4*)ws;
    #pragma unroll
    for (int j = 0; j < 7; ++j)
      wlds[j * 256 + tid] = wsrc[j * 256 + tid];
  }
  __syncthreads();

  float fcw_l[NTILES];
  #pragma unroll
  for (int nt = 0; nt < NTILES; ++nt) {
    const int n = nt * 16 + col;
    fcw_l[nt] = (n < KOUT) ? fc_w[n] * 0.015625f : 0.0f;
  }

  f32x4 acc[NTILES];
  #pragma unroll
  for (int nt = 0; nt < NTILES; ++nt) acc[nt] = (f32x4){0.f, 0.f, 0.f, 0.f};
  const uint2* wl2 = (const uint2*)wlds;

  #pragma unroll
  for (int ks = 0; ks < 8; ++ks) {
    const float4* rp = (const float4*)(route_table + ri * DIM + ks * 32 + quad * 8);
    const float4* tp = (const float4*)(time_table  + ti * DIM + ks * 32 + quad * 8);
    float4 r0 = rp[0], r1 = rp[1], t0 = tp[0], t1 = tp[1];
    uint32_t p0 = 0, p1 = 0;
    p0 = __builtin_amdgcn_cvt_pk_fp8_f32(64.f * r0.x * t0.x, 64.f * r0.y * t0.y, p0, false);
    p0 = __builtin_amdgcn_cvt_pk_fp8_f32(64.f * r0.z * t0.z, 64.f * r0.w * t0.w, p0, true);
    p1 = __builtin_amdgcn_cvt_pk_fp8_f32(64.f * r1.x * t1.x, 64.f * r1.y * t1.y, p1, false);
    p1 = __builtin_amdgcn_cvt_pk_fp8_f32(64.f * r1.z * t1.z, 64.f * r1.w * t1.w, p1, true);
    const long a64 = __builtin_bit_cast(long, make_uint2(p0, p1));
    #pragma unroll
    for (int nt = 0; nt < NTILES; ++nt) {
      const long b64 = __builtin_bit_cast(long, wl2[(ks * NTILES + nt) * 64 + lane]);
      acc[nt] = __builtin_amdgcn_mfma_f32_16x16x32_fp8_fp8(a64, b64, acc[nt], 0, 0, 0);
    }
  }

  float s[4];
  #pragma unroll
  for (int reg = 0; reg < 4; ++reg) {
    float v = 0.f;
    #pragma unroll
    for (int nt = 0; nt < NTILES; ++nt)
      v += fmaxf(acc[nt][reg], 0.f) * fcw_l[nt];
    s[reg] = sum16_all(v);
  }

  const float rav[5] = {ra0.x, ra0.y, ra0.z, ra0.w, ra4};
  const float tbv[5] = {tb0.x, tb0.y, tb0.z, tb0.w, tb4};
  const float rq = (quad & 2) ? ((quad & 1) ? rav[3] : rav[2])
                              : ((quad & 1) ? rav[1] : rav[0]);
  const float tq = (quad & 2) ? ((quad & 1) ? tbv[3] : tbv[2])
                              : ((quad & 1) ? tbv[1] : tbv[0]);
  float sig = 0.f;
  #pragma unroll
  for (int j = 0; j < 5; ++j)
    sig += sigm(rq * tbv[j] + mode_bias[5 * quad + j]) * fc_w[KOUT + 5 * quad + j];
  sig += sigm(rav[4] * tq + mode_bias[20 + quad]) * fc_w[KOUT + 20 + quad];
  if (quad == 0)
    sig += sigm(rav[4] * tbv[4] + mode_bias[24]) * fc_w[KOUT + 24];
  sig += __shfl_xor(sig, 16, 64);
  sig += __shfl_xor(sig, 32, 64);

  if (quad == (col >> 2)) {
    const float sa = (col & 1) ? s[1] : s[0];
    const float sb = (col & 1) ? s[3] : s[2];
    const float gcp = (col & 2) ? sb : sa;
    out[m0 + col] = fc_b[0] + gcp + sig;
  }
}

// ---------------------------------------------------------------------------
extern "C" void kernel_launch(void* const* d_in, const int* in_sizes, int n_in,
                              void* d_out, int out_size, void* d_ws, size_t ws_size,
                              hipStream_t stream)
{
  const int*   route_idx   = (const int*)d_in[0];
  const int*   time_idx    = (const int*)d_in[1];
  const float* route_table = (const float*)d_in[2];
  const float* time_table  = (const float*)d_in[3];
  const float* w           = (const float*)d_in[4];
  const float* mode_a      = (const float*)d_in[5];
  const float* mode_b      = (const float*)d_in[6];
  const float* mode_bias   = (const float*)d_in[7];
  const float* fc_w        = (const float*)d_in[8];
  const float* fc_b        = (const float*)d_in[9];
  uint8_t* ws  = (uint8_t*)d_ws;
  float*   out = (float*)d_out;

  const int big = (ws_size >= WS_NEED) ? 1 : 0;   // constant across calls

  // 14 (w frags) + 63 (time, 32 rows/blk) + 3125 (route, 32 rows/blk)
  if (big) {
    prep_kernel<1><<<3202, 256, 0, stream>>>(route_table, time_table, w,
                                             mode_a, mode_b, ws);
    main_pipelined<<<BATCH / 256, 256, 0, stream>>>(route_idx, time_idx,
                                                    mode_bias, fc_w, fc_b, ws, out);
  } else {
    prep_kernel<0><<<3202, 256, 0, stream>>>(route_table, time_table, w,
                                             mode_a, mode_b, ws);
    main_fallback<<<BATCH / 64, 256, 0, stream>>>(route_idx, time_idx,
                                                  route_table, time_table,
                                                  mode_bias, fc_w, fc_b, ws, out);
  }
}